// Round 5
// baseline (130.049 us; speedup 1.0000x reference)
//
#include <hip/hip_runtime.h>

// Problem constants (from reference): B=4, C=5, H=64, W=64, N=4096
#define Bq  4
#define Cc  5
#define Hh  64
#define Ww  64
#define HW  (Hh * Ww)       // 4096
#define CHW (Cc * HW)       // 20480
#define HW4 (HW / 4)        // 1024 float4 per plane
#define NQMAX 4096          // max bucketable queries
#define Gq  8               // queries per workgroup in grouped attention
#define WSPLIT 4            // waves per block = key splits

__device__ __forceinline__ float fast_exp2(float x) {
#if __has_builtin(__builtin_amdgcn_exp2f)
    return __builtin_amdgcn_exp2f(x);
#else
    return exp2f(x);
#endif
}

// ---------------------------------------------------------------------------
// Kernel A: K/V precompute + fused y=x copy + query resolution.
// SCALAR layout: one thread per (b,p) -> 16384 threads = 256 waves (4x the
// wave count of the f4 version; this kernel is latency-bound, not BW-bound).
// All loads/stores stride-1 in p -> fully coalesced.
// First NQMAX threads also resolve query t: ballot per batch, leader lane
// does one atomicAdd to reserve a contiguous range in qrec[b][...], lanes
// write resolved spatial positions. Order within qrec is non-deterministic
// but each query's output depends only on (b,pos) -> safe.
// ---------------------------------------------------------------------------
__global__ __launch_bounds__(256) void prep_scalar(
    const float* __restrict__ x,
    const float* __restrict__ kw, const float* __restrict__ kb,
    const float* __restrict__ vw, const float* __restrict__ vb,
    const int* __restrict__ idx_b, const int* __restrict__ idx_h,
    const int* __restrict__ idx_w, int N,
    float* __restrict__ K, float* __restrict__ V, float* __restrict__ y,
    int* __restrict__ qrec,      // [Bq][NQMAX] resolved positions
    int* __restrict__ qcnt)      // [Bq] atomic counters (pre-zeroed)
{
    int t = blockIdx.x * blockDim.x + threadIdx.x;   // 0..16383
    if (t < Bq * HW) {
        int b = t >> 12;            // / HW
        int p = t & (HW - 1);       // % HW
        const int base = b * CHW;
        float xi[Cc];
#pragma unroll
        for (int c = 0; c < Cc; ++c) {
            xi[c] = x[base + c * HW + p];
            y[base + c * HW + p] = xi[c];       // fused y = x copy
        }
#pragma unroll
        for (int o = 0; o < Cc; ++o) {
            float ka = kb[o], va = vb[o];
#pragma unroll
            for (int c = 0; c < Cc; ++c) {
                ka += kw[o * Cc + c] * xi[c];
                va += vw[o * Cc + c] * xi[c];
            }
            K[base + o * HW + p] = ka;
            V[base + o * HW + p] = va;
        }
    }

    // ---- resolve queries into per-batch position lists (threads 0..NQMAX) --
    if (t < NQMAX) {
        int lane = threadIdx.x & 63;
        int myb  = (t < N) ? idx_b[t] : -1;
        int pos  = (t < N) ? (idx_h[t] * Ww + idx_w[t]) : 0;
#pragma unroll
        for (int b = 0; b < Bq; ++b) {
            unsigned long long mask = __ballot(myb == b);
            int cnt = (int)__popcll(mask);
            if (cnt) {
                int leader = __ffsll((long long)mask) - 1;   // wave-uniform
                int base = 0;
                if (lane == leader) base = atomicAdd(&qcnt[b], cnt);
                base = __shfl(base, leader, 64);
                if (myb == b) {
                    int rank = (int)__popcll(mask & ((1ull << lane) - 1ull));
                    qrec[b * NQMAX + base + rank] = pos;
                }
            }
        }
    }
}

// ---------------------------------------------------------------------------
// Kernel B: grouped key-split attention, v3.
// One 256-thread block = 4 waves handles Gq=8 queries of ONE batch; wave w
// owns a disjoint quarter of the 1024 float4 key-groups (4 iterations, but
// each iteration carries 8 queries of arithmetic -> loads hide under VALU).
// 515 blocks = 2048 waves = 2 waves/SIMD chip-wide.
// Prologue: 4 scalar qcnt loads -> scalar (b,g) map -> 8 broadcast qrec
// loads. No ballots, no prefix sums, no dependent-load chains.
// Online softmax in log2 domain; in-wave butterfly reduce; LDS cross-wave
// combine; 40-thread scatter.
// ---------------------------------------------------------------------------
__global__ __launch_bounds__(256) void attn_v3(
    const float* __restrict__ x,
    const float* __restrict__ qw, const float* __restrict__ qb,
    const float4* __restrict__ K4, const float4* __restrict__ V4,
    const float* __restrict__ gamma,
    const int* __restrict__ qrec, const int* __restrict__ qcnt,
    float* __restrict__ y)
{
    __shared__ float sm_part[WSPLIT][Gq][7];  // [wave][query][m, l, acc0..4]
    __shared__ int   spos[Gq];                // resolved positions (-1 invalid)

    const int lane = threadIdx.x & 63;
    const int w    = threadIdx.x >> 6;        // wave 0..3

    // ---- scalar blockIdx -> (batch b, group g) map ----
    int cb[Bq];
    cb[0] = qcnt[0]; cb[1] = qcnt[1]; cb[2] = qcnt[2]; cb[3] = qcnt[3];
    int r = blockIdx.x, b = -1, total = 0;
#pragma unroll
    for (int bb = 0; bb < Bq; ++bb) {
        int gb = (cb[bb] + Gq - 1) / Gq;
        if (b < 0) {
            if (r < gb) { b = bb; total = cb[bb]; }
            else        { r -= gb; }
        }
    }
    if (b < 0) return;                        // uniform across block
    const int g = r;

    // ---- fetch Gq resolved positions (one broadcast load each) ----
    int  pos[Gq];
    bool qv[Gq];
#pragma unroll
    for (int j = 0; j < Gq; ++j) {
        int rr = g * Gq + j;
        qv[j]  = (rr < total);                // uniform
        pos[j] = qv[j] ? qrec[b * NQMAX + rr] : -1;
        if (threadIdx.x == 0) spos[j] = pos[j];   // static index j
    }

    // ---- q vectors (log2e folded); broadcast loads ----
    const float LOG2E = 1.4426950408889634f;
    float q2[Gq][Cc];
#pragma unroll
    for (int j = 0; j < Gq; ++j) {
        if (qv[j]) {
            float xq[Cc];
#pragma unroll
            for (int c = 0; c < Cc; ++c) xq[c] = x[b * CHW + c * HW + pos[j]];
#pragma unroll
            for (int o = 0; o < Cc; ++o) {
                float a = qb[o];
#pragma unroll
                for (int c = 0; c < Cc; ++c) a += qw[o * Cc + c] * xq[c];
                q2[j][o] = a * LOG2E;
            }
        } else {
#pragma unroll
            for (int o = 0; o < Cc; ++o) q2[j][o] = 0.f;
        }
    }

    const float4* Kb = K4 + b * (Cc * HW4);
    const float4* Vb = V4 + b * (Cc * HW4);
    const int p0 = w * (HW4 / WSPLIT) + lane;

    float m[Gq], l[Gq], acc[Gq][Cc];
#pragma unroll
    for (int j = 0; j < Gq; ++j) {
        m[j] = -1e30f; l[j] = 0.f;
#pragma unroll
        for (int c = 0; c < Cc; ++c) acc[j][c] = 0.f;
    }

    // ---- main loop: 4 iterations, 10 loads + ~8x58 VALU ops each ----
#pragma unroll
    for (int it = 0; it < (HW4 / WSPLIT) / 64; ++it) {
        int p = p0 + it * 64;
        float4 kc[Cc], vc[Cc];
#pragma unroll
        for (int c = 0; c < Cc; ++c) {
            kc[c] = Kb[c * HW4 + p];
            vc[c] = Vb[c * HW4 + p];
        }
#pragma unroll
        for (int j = 0; j < Gq; ++j) {
            float ex = q2[j][0]*kc[0].x + q2[j][1]*kc[1].x + q2[j][2]*kc[2].x
                     + q2[j][3]*kc[3].x + q2[j][4]*kc[4].x;
            float ey = q2[j][0]*kc[0].y + q2[j][1]*kc[1].y + q2[j][2]*kc[2].y
                     + q2[j][3]*kc[3].y + q2[j][4]*kc[4].y;
            float ez = q2[j][0]*kc[0].z + q2[j][1]*kc[1].z + q2[j][2]*kc[2].z
                     + q2[j][3]*kc[3].z + q2[j][4]*kc[4].z;
            float ew = q2[j][0]*kc[0].w + q2[j][1]*kc[1].w + q2[j][2]*kc[2].w
                     + q2[j][3]*kc[3].w + q2[j][4]*kc[4].w;

            float m4 = fmaxf(fmaxf(ex, ey), fmaxf(ez, ew));
            float nm = fmaxf(m[j], m4);
            float a  = fast_exp2(m[j] - nm);
            float w0 = fast_exp2(ex - nm);
            float w1 = fast_exp2(ey - nm);
            float w2 = fast_exp2(ez - nm);
            float w3 = fast_exp2(ew - nm);
            l[j] = l[j] * a + ((w0 + w1) + (w2 + w3));
#pragma unroll
            for (int c = 0; c < Cc; ++c)
                acc[j][c] = acc[j][c] * a +
                            ((w0 * vc[c].x + w1 * vc[c].y) +
                             (w2 * vc[c].z + w3 * vc[c].w));
            m[j] = nm;
        }
    }

    // ---- in-wave reduce (max-first), drop per-wave partials to LDS ----
#pragma unroll
    for (int j = 0; j < Gq; ++j) {
        float mm = m[j];
#pragma unroll
        for (int off = 32; off >= 1; off >>= 1)
            mm = fmaxf(mm, __shfl_xor(mm, off, 64));
        float a  = fast_exp2(m[j] - mm);
        float ll = l[j] * a;
        float ac[Cc];
#pragma unroll
        for (int c = 0; c < Cc; ++c) ac[c] = acc[j][c] * a;
#pragma unroll
        for (int off = 32; off >= 1; off >>= 1) {
            ll += __shfl_xor(ll, off, 64);
#pragma unroll
            for (int c = 0; c < Cc; ++c) ac[c] += __shfl_xor(ac[c], off, 64);
        }
        if (lane == 0) {
            sm_part[w][j][0] = mm;
            sm_part[w][j][1] = ll;
#pragma unroll
            for (int c = 0; c < Cc; ++c) sm_part[w][j][2 + c] = ac[c];
        }
    }
    __syncthreads();

    // ---- cross-wave combine + scatter: one thread per (query, channel) ----
    const int tid = threadIdx.x;
    if (tid < Gq * Cc) {
        int j = tid / Cc, c = tid % Cc;
        int pp = spos[j];                     // LDS dynamic index: fine
        if (pp >= 0) {
            float m0 = sm_part[0][j][0], m1 = sm_part[1][j][0];
            float m2 = sm_part[2][j][0], m3 = sm_part[3][j][0];
            float mmax = fmaxf(fmaxf(m0, m1), fmaxf(m2, m3));
            float a0 = fast_exp2(m0 - mmax), a1 = fast_exp2(m1 - mmax);
            float a2 = fast_exp2(m2 - mmax), a3 = fast_exp2(m3 - mmax);
            float lsum = sm_part[0][j][1]*a0 + sm_part[1][j][1]*a1
                       + sm_part[2][j][1]*a2 + sm_part[3][j][1]*a3;
            float asum = sm_part[0][j][2+c]*a0 + sm_part[1][j][2+c]*a1
                       + sm_part[2][j][2+c]*a2 + sm_part[3][j][2+c]*a3;
            float xi = x[b * CHW + c * HW + pp];
            y[b * CHW + c * HW + pp] = gamma[0] * (asum / lsum) + xi;
        }
    }
}

// ---------------------------------------------------------------------------
// Fallback (no/small workspace or oversized N): scalar inline-KV path.
// ---------------------------------------------------------------------------
__global__ void attn_scatter_inline(
    const float* __restrict__ x,
    const float* __restrict__ qw, const float* __restrict__ qb,
    const float* __restrict__ kw, const float* __restrict__ kb,
    const float* __restrict__ vw, const float* __restrict__ vb,
    const float* __restrict__ gamma,
    const int* __restrict__ idx_b, const int* __restrict__ idx_h,
    const int* __restrict__ idx_w,
    float* __restrict__ y, int N)
{
    int gtid = blockIdx.x * blockDim.x + threadIdx.x;
    int n    = gtid >> 6;
    int lane = threadIdx.x & 63;
    if (n >= N) return;

    const int b   = idx_b[n];
    const int pos = idx_h[n] * Ww + idx_w[n];

    float xq[Cc];
#pragma unroll
    for (int c = 0; c < Cc; ++c) xq[c] = x[b * CHW + c * HW + pos];
    float q[Cc];
#pragma unroll
    for (int o = 0; o < Cc; ++o) {
        float a = qb[o];
#pragma unroll
        for (int c = 0; c < Cc; ++c) a += qw[o * Cc + c] * xq[c];
        q[o] = a;
    }

    const float* Xb = x + b * CHW;
    float m = -1e30f, l = 0.f;
    float acc[Cc] = {0.f, 0.f, 0.f, 0.f, 0.f};

    for (int p = lane; p < HW; p += 64) {
        float xi[Cc];
#pragma unroll
        for (int c = 0; c < Cc; ++c) xi[c] = Xb[c * HW + p];
        float kv_k[Cc], kv_v[Cc];
#pragma unroll
        for (int o = 0; o < Cc; ++o) {
            float ka = kb[o], va = vb[o];
#pragma unroll
            for (int c = 0; c < Cc; ++c) {
                ka += kw[o * Cc + c] * xi[c];
                va += vw[o * Cc + c] * xi[c];
            }
            kv_k[o] = ka;
            kv_v[o] = va;
        }
        float e = q[0]*kv_k[0] + q[1]*kv_k[1] + q[2]*kv_k[2] + q[3]*kv_k[3] + q[4]*kv_k[4];
        float nm  = fmaxf(m, e);
        float a   = __expf(m - nm);
        float wgt = __expf(e - nm);
        l = l * a + wgt;
#pragma unroll
        for (int c = 0; c < Cc; ++c) acc[c] = acc[c] * a + wgt * kv_v[c];
        m = nm;
    }

#pragma unroll
    for (int off = 32; off >= 1; off >>= 1) {
        float m2 = __shfl_xor(m, off, 64);
        float l2 = __shfl_xor(l, off, 64);
        float nm = fmaxf(m, m2);
        float a  = __expf(m - nm);
        float a2 = __expf(m2 - nm);
        l = l * a + l2 * a2;
#pragma unroll
        for (int c = 0; c < Cc; ++c) {
            float o2 = __shfl_xor(acc[c], off, 64);
            acc[c] = acc[c] * a + o2 * a2;
        }
        m = nm;
    }

    if (lane < Cc) {
        int c = lane;
        float xi = x[b * CHW + c * HW + pos];
        y[b * CHW + c * HW + pos] = gamma[0] * (acc[c] / l) + xi;
    }
}

// ---------------------------------------------------------------------------
extern "C" void kernel_launch(void* const* d_in, const int* in_sizes, int n_in,
                              void* d_out, int out_size, void* d_ws, size_t ws_size,
                              hipStream_t stream) {
    const float* x     = (const float*)d_in[0];
    // d_in[1] = x_teature: unused by the reference
    const float* qw    = (const float*)d_in[2];
    const float* qb    = (const float*)d_in[3];
    const float* kw    = (const float*)d_in[4];
    const float* kb    = (const float*)d_in[5];
    const float* vw    = (const float*)d_in[6];
    const float* vb    = (const float*)d_in[7];
    const float* gamma = (const float*)d_in[8];
    const int*   idx_b = (const int*)d_in[9];
    const int*   idx_h = (const int*)d_in[10];
    const int*   idx_w = (const int*)d_in[11];
    const int    N     = in_sizes[9];   // idx_b element count (= index_len)

    float* y = (float*)d_out;

    // workspace layout: K | V | qrec | qcnt
    const size_t kv_floats = (size_t)Bq * CHW;                 // per map
    const size_t need = 2 * kv_floats * sizeof(float)
                      + (size_t)(Bq * NQMAX + Bq) * sizeof(int);

    if (ws_size >= need && N <= NQMAX) {
        float* K = (float*)d_ws;
        float* V = K + kv_floats;
        int* qrec = (int*)(V + kv_floats);
        int* qcnt = qrec + (size_t)Bq * NQMAX;

        hipMemsetAsync(qcnt, 0, Bq * sizeof(int), stream);

        prep_scalar<<<(Bq * HW + 255) / 256, 256, 0, stream>>>(
            x, kw, kb, vw, vb, idx_b, idx_h, idx_w, N,
            K, V, y, qrec, qcnt);

        // one block per group of Gq queries; +Bq-1 covers per-batch ceil slack
        const int blocks = (N + Gq - 1) / Gq + (Bq - 1);
        attn_v3<<<blocks, 256, 0, stream>>>(
            x, qw, qb, (const float4*)K, (const float4*)V, gamma,
            qrec, qcnt, y);
    } else {
        hipMemcpyAsync(y, x, (size_t)Bq * CHW * sizeof(float),
                       hipMemcpyDeviceToDevice, stream);
        const int grid_b = (N + 3) / 4;         // 4 waves per 256-thread block
        attn_scatter_inline<<<grid_b, 256, 0, stream>>>(
            x, qw, qb, kw, kb, vw, vb, gamma, idx_b, idx_h, idx_w, y, N);
    }
}

// Round 6
// 107.992 us; speedup vs baseline: 1.2042x; 1.2042x over previous
//
#include <hip/hip_runtime.h>

// Problem constants (from reference): B=4, C=5, H=64, W=64, N=4096
#define Bq  4
#define Cc  5
#define Hh  64
#define Ww  64
#define HW  (Hh * Ww)       // 4096
#define CHW (Cc * HW)       // 20480
#define HW4 (HW / 4)        // 1024 float4 per plane

__device__ __forceinline__ float fast_exp2(float x) {
#if __has_builtin(__builtin_amdgcn_exp2f)
    return __builtin_amdgcn_exp2f(x);
#else
    return exp2f(x);
#endif
}

// ---------------------------------------------------------------------------
// Kernel A: K/V map precompute, float4 over spatial dim, with fused y = x
// copy. One thread per (b, p4) group of 4 spatial positions.
// (Byte-identical to the round-1 version, which measured best overall.)
// ---------------------------------------------------------------------------
__global__ __launch_bounds__(256) void prep_f4(
    const float4* __restrict__ x4,
    const float* __restrict__ kw, const float* __restrict__ kb,
    const float* __restrict__ vw, const float* __restrict__ vb,
    float4* __restrict__ K4, float4* __restrict__ V4,
    float4* __restrict__ y4)
{
    int t = blockIdx.x * blockDim.x + threadIdx.x;
    if (t >= Bq * HW4) return;
    int b = t >> 10;            // / HW4
    int p = t & (HW4 - 1);      // % HW4
    const int base = b * (Cc * HW4);

    float4 xi[Cc];
#pragma unroll
    for (int c = 0; c < Cc; ++c) {
        xi[c] = x4[base + c * HW4 + p];
        y4[base + c * HW4 + p] = xi[c];     // fused y = x copy
    }
#pragma unroll
    for (int o = 0; o < Cc; ++o) {
        float kbo = kb[o], vbo = vb[o];
        float4 ka = {kbo, kbo, kbo, kbo};
        float4 va = {vbo, vbo, vbo, vbo};
#pragma unroll
        for (int c = 0; c < Cc; ++c) {
            float kwv = kw[o * Cc + c];
            float vwv = vw[o * Cc + c];
            ka.x += kwv * xi[c].x; ka.y += kwv * xi[c].y;
            ka.z += kwv * xi[c].z; ka.w += kwv * xi[c].w;
            va.x += vwv * xi[c].x; va.y += vwv * xi[c].y;
            va.z += vwv * xi[c].z; va.w += vwv * xi[c].w;
        }
        K4[base + o * HW4 + p] = ka;
        V4[base + o * HW4 + p] = va;
    }
}

// ---------------------------------------------------------------------------
// Kernel B: key-split wave-per-(query,half) attention.
// Block = 256 threads = 4 waves = 2 queries x 2 key-halves.
//   wave w: query qi = w>>1 (n = blockIdx.x*2 + qi), half h = w&1.
// Each wave streams its half of the keys (8 iterations of 64 float4),
// r1-identical online softmax in log2 domain, max-first butterfly in-wave,
// then a 56-byte LDS merge across the half-pair and a 10-thread scatter.
// 8192 waves total (2x round-1) -> double the latency-hiding parallelism
// with the same minimal per-wave prologue and low VGPR count.
// ---------------------------------------------------------------------------
__global__ __launch_bounds__(256) void attn_split2(
    const float* __restrict__ x,
    const float* __restrict__ qw, const float* __restrict__ qb,
    const float4* __restrict__ K4, const float4* __restrict__ V4,
    const float* __restrict__ gamma,
    const int* __restrict__ idx_b, const int* __restrict__ idx_h,
    const int* __restrict__ idx_w,
    float* __restrict__ y, int N)
{
    __shared__ float sm[2][2][7];   // [query][half][m, l, acc0..4]
    __shared__ int   sinfo[2][2];   // [query][b, pos]

    const int lane = threadIdx.x & 63;
    const int w    = threadIdx.x >> 6;     // wave 0..3
    const int qi   = w >> 1;               // query slot 0..1
    const int h    = w & 1;                // key half 0..1
    const int n    = blockIdx.x * 2 + qi;
    const bool valid = (n < N);            // wave-uniform

    int b = 0, pos = 0;
    if (valid) {
        b   = idx_b[n];
        pos = idx_h[n] * Ww + idx_w[n];
        if (lane == 0 && h == 0) { sinfo[qi][0] = b; sinfo[qi][1] = pos; }
    } else if (lane == 0 && h == 0) {
        sinfo[qi][0] = -1; sinfo[qi][1] = 0;
    }

    // q[o] = (sum_c qw[o,c]*x[b,c,pos] + qb[o]) * log2e  (broadcast loads)
    const float LOG2E = 1.4426950408889634f;
    float q2[Cc];
    if (valid) {
        float xq[Cc];
#pragma unroll
        for (int c = 0; c < Cc; ++c) xq[c] = x[b * CHW + c * HW + pos];
#pragma unroll
        for (int o = 0; o < Cc; ++o) {
            float a = qb[o];
#pragma unroll
            for (int c = 0; c < Cc; ++c) a += qw[o * Cc + c] * xq[c];
            q2[o] = a * LOG2E;
        }
    } else {
#pragma unroll
        for (int o = 0; o < Cc; ++o) q2[o] = 0.f;
    }

    const float4* Kb = K4 + b * (Cc * HW4);
    const float4* Vb = V4 + b * (Cc * HW4);

    float m = -1e30f, l = 0.f;
    float acc[Cc] = {0.f, 0.f, 0.f, 0.f, 0.f};

    if (valid) {
        const int p0 = h * (HW4 / 2) + lane;
#pragma unroll 2
        for (int it = 0; it < (HW4 / 2) / 64; ++it) {   // 8 iterations
            int p = p0 + it * 64;
            float4 kc[Cc], vc[Cc];
#pragma unroll
            for (int c = 0; c < Cc; ++c) {
                kc[c] = Kb[c * HW4 + p];
                vc[c] = Vb[c * HW4 + p];
            }
            float ex = q2[0]*kc[0].x + q2[1]*kc[1].x + q2[2]*kc[2].x
                     + q2[3]*kc[3].x + q2[4]*kc[4].x;
            float ey = q2[0]*kc[0].y + q2[1]*kc[1].y + q2[2]*kc[2].y
                     + q2[3]*kc[3].y + q2[4]*kc[4].y;
            float ez = q2[0]*kc[0].z + q2[1]*kc[1].z + q2[2]*kc[2].z
                     + q2[3]*kc[3].z + q2[4]*kc[4].z;
            float ew = q2[0]*kc[0].w + q2[1]*kc[1].w + q2[2]*kc[2].w
                     + q2[3]*kc[3].w + q2[4]*kc[4].w;

            float m4 = fmaxf(fmaxf(ex, ey), fmaxf(ez, ew));
            float nm = fmaxf(m, m4);
            float a  = fast_exp2(m - nm);
            float w0 = fast_exp2(ex - nm);
            float w1 = fast_exp2(ey - nm);
            float w2 = fast_exp2(ez - nm);
            float w3 = fast_exp2(ew - nm);
            l = l * a + ((w0 + w1) + (w2 + w3));
#pragma unroll
            for (int c = 0; c < Cc; ++c)
                acc[c] = acc[c] * a +
                         ((w0 * vc[c].x + w1 * vc[c].y) +
                          (w2 * vc[c].z + w3 * vc[c].w));
            m = nm;
        }
    }

    // ---- in-wave reduce: max-first (1 exp + plain-sum butterflies) ----
    {
        float mm = m;
#pragma unroll
        for (int off = 32; off >= 1; off >>= 1)
            mm = fmaxf(mm, __shfl_xor(mm, off, 64));
        float a  = fast_exp2(m - mm);
        float ll = l * a;
        float ac[Cc];
#pragma unroll
        for (int c = 0; c < Cc; ++c) ac[c] = acc[c] * a;
#pragma unroll
        for (int off = 32; off >= 1; off >>= 1) {
            ll += __shfl_xor(ll, off, 64);
#pragma unroll
            for (int c = 0; c < Cc; ++c) ac[c] += __shfl_xor(ac[c], off, 64);
        }
        if (lane == 0) {
            sm[qi][h][0] = mm;
            sm[qi][h][1] = ll;
#pragma unroll
            for (int c = 0; c < Cc; ++c) sm[qi][h][2 + c] = ac[c];
        }
    }
    __syncthreads();

    // ---- merge halves + scatter: one thread per (query, channel) ----
    const int tid = threadIdx.x;
    if (tid < 2 * Cc) {
        int j = tid / Cc, c = tid % Cc;
        int bb = sinfo[j][0];
        if (bb >= 0) {
            int pp = sinfo[j][1];
            float m0 = sm[j][0][0], m1 = sm[j][1][0];
            float mmax = fmaxf(m0, m1);
            float a0 = fast_exp2(m0 - mmax), a1 = fast_exp2(m1 - mmax);
            float lsum = sm[j][0][1] * a0 + sm[j][1][1] * a1;
            float asum = sm[j][0][2 + c] * a0 + sm[j][1][2 + c] * a1;
            float xi = x[bb * CHW + c * HW + pp];
            y[bb * CHW + c * HW + pp] = gamma[0] * (asum / lsum) + xi;
        }
    }
}

// ---------------------------------------------------------------------------
// Fallback (no/small workspace): scalar inline-KV path.
// ---------------------------------------------------------------------------
__global__ void attn_scatter_inline(
    const float* __restrict__ x,
    const float* __restrict__ qw, const float* __restrict__ qb,
    const float* __restrict__ kw, const float* __restrict__ kb,
    const float* __restrict__ vw, const float* __restrict__ vb,
    const float* __restrict__ gamma,
    const int* __restrict__ idx_b, const int* __restrict__ idx_h,
    const int* __restrict__ idx_w,
    float* __restrict__ y, int N)
{
    int gtid = blockIdx.x * blockDim.x + threadIdx.x;
    int n    = gtid >> 6;
    int lane = threadIdx.x & 63;
    if (n >= N) return;

    const int b   = idx_b[n];
    const int pos = idx_h[n] * Ww + idx_w[n];

    float xq[Cc];
#pragma unroll
    for (int c = 0; c < Cc; ++c) xq[c] = x[b * CHW + c * HW + pos];
    float q[Cc];
#pragma unroll
    for (int o = 0; o < Cc; ++o) {
        float a = qb[o];
#pragma unroll
        for (int c = 0; c < Cc; ++c) a += qw[o * Cc + c] * xq[c];
        q[o] = a;
    }

    const float* Xb = x + b * CHW;
    float m = -1e30f, l = 0.f;
    float acc[Cc] = {0.f, 0.f, 0.f, 0.f, 0.f};

    for (int p = lane; p < HW; p += 64) {
        float xi[Cc];
#pragma unroll
        for (int c = 0; c < Cc; ++c) xi[c] = Xb[c * HW + p];
        float kv_k[Cc], kv_v[Cc];
#pragma unroll
        for (int o = 0; o < Cc; ++o) {
            float ka = kb[o], va = vb[o];
#pragma unroll
            for (int c = 0; c < Cc; ++c) {
                ka += kw[o * Cc + c] * xi[c];
                va += vw[o * Cc + c] * xi[c];
            }
            kv_k[o] = ka;
            kv_v[o] = va;
        }
        float e = q[0]*kv_k[0] + q[1]*kv_k[1] + q[2]*kv_k[2] + q[3]*kv_k[3] + q[4]*kv_k[4];
        float nm  = fmaxf(m, e);
        float a   = __expf(m - nm);
        float wgt = __expf(e - nm);
        l = l * a + wgt;
#pragma unroll
        for (int c = 0; c < Cc; ++c) acc[c] = acc[c] * a + wgt * kv_v[c];
        m = nm;
    }

#pragma unroll
    for (int off = 32; off >= 1; off >>= 1) {
        float m2 = __shfl_xor(m, off, 64);
        float l2 = __shfl_xor(l, off, 64);
        float nm = fmaxf(m, m2);
        float a  = __expf(m - nm);
        float a2 = __expf(m2 - nm);
        l = l * a + l2 * a2;
#pragma unroll
        for (int c = 0; c < Cc; ++c) {
            float o2 = __shfl_xor(acc[c], off, 64);
            acc[c] = acc[c] * a + o2 * a2;
        }
        m = nm;
    }

    if (lane < Cc) {
        int c = lane;
        float xi = x[b * CHW + c * HW + pos];
        y[b * CHW + c * HW + pos] = gamma[0] * (acc[c] / l) + xi;
    }
}

// ---------------------------------------------------------------------------
extern "C" void kernel_launch(void* const* d_in, const int* in_sizes, int n_in,
                              void* d_out, int out_size, void* d_ws, size_t ws_size,
                              hipStream_t stream) {
    const float* x     = (const float*)d_in[0];
    // d_in[1] = x_teature: unused by the reference
    const float* qw    = (const float*)d_in[2];
    const float* qb    = (const float*)d_in[3];
    const float* kw    = (const float*)d_in[4];
    const float* kb    = (const float*)d_in[5];
    const float* vw    = (const float*)d_in[6];
    const float* vb    = (const float*)d_in[7];
    const float* gamma = (const float*)d_in[8];
    const int*   idx_b = (const int*)d_in[9];
    const int*   idx_h = (const int*)d_in[10];
    const int*   idx_w = (const int*)d_in[11];
    const int    N     = in_sizes[9];   // idx_b element count (= index_len)

    float* y = (float*)d_out;

    const size_t kv_bytes = (size_t)2 * Bq * CHW * sizeof(float); // 640 KB

    if (ws_size >= kv_bytes) {
        float* K = (float*)d_ws;
        float* V = K + (size_t)Bq * CHW;
        prep_f4<<<(Bq * HW4 + 255) / 256, 256, 0, stream>>>(
            (const float4*)x, kw, kb, vw, vb, (float4*)K, (float4*)V, (float4*)y);

        // one block per 2 queries (4 waves = 2 queries x 2 key-halves)
        const int blocks = (N + 1) / 2;
        attn_split2<<<blocks, 256, 0, stream>>>(
            x, qw, qb, (const float4*)K, (const float4*)V, gamma,
            idx_b, idx_h, idx_w, y, N);
    } else {
        hipMemcpyAsync(y, x, (size_t)Bq * CHW * sizeof(float),
                       hipMemcpyDeviceToDevice, stream);
        const int grid_b = (N + 3) / 4;         // 4 waves per 256-thread block
        attn_scatter_inline<<<grid_b, 256, 0, stream>>>(
            x, qw, qb, kw, kb, vw, vb, gamma, idx_b, idx_h, idx_w, y, N);
    }
}

// Round 7
// 94.002 us; speedup vs baseline: 1.3835x; 1.1488x over previous
//
#include <hip/hip_runtime.h>

// Problem constants (from reference): B=4, C=5, H=64, W=64, N=4096
#define Bq  4
#define Cc  5
#define Hh  64
#define Ww  64
#define HW  (Hh * Ww)       // 4096
#define CHW (Cc * HW)       // 20480
#define HW4 (HW / 4)        // 1024 float4 per plane

__device__ __forceinline__ float fast_exp2(float x) {
#if __has_builtin(__builtin_amdgcn_exp2f)
    return __builtin_amdgcn_exp2f(x);
#else
    return exp2f(x);
#endif
}

// ---------------------------------------------------------------------------
// Direct attention: K and V are never materialized.
//   energy[n,p] = qk·x[b,:,p] (+const, dropped: softmax shift-invariant)
//     where qk[c] = sum_o q[n,o]*kw[o,c],  q[n,o] = sum_c qw[o,c]x[c,pos]+qb[o]
//   out[n,c'] = (sum_c vw[c',c]*A[c])/l + vb[c']
//     where A[c] = sum_p w_p*x[b,c,p], l = sum_p w_p  (unnormalized weights)
// One 64-lane wave per query n (r1's winning structure: 4096 skinny waves),
// streaming x directly as float4 — 5 loads/iter instead of 10 (L2 bytes /2).
// Online softmax in log2 domain (log2e folded into qk); max-first butterfly;
// 5-lane epilogue applies vw/vb and scatters gamma*out + xi into y.
// ---------------------------------------------------------------------------
__global__ __launch_bounds__(256) void attn_direct(
    const float* __restrict__ x, const float4* __restrict__ x4,
    const float* __restrict__ qw, const float* __restrict__ qb,
    const float* __restrict__ kw,
    const float* __restrict__ vw, const float* __restrict__ vb,
    const float* __restrict__ gamma,
    const int* __restrict__ idx_b, const int* __restrict__ idx_h,
    const int* __restrict__ idx_w,
    float* __restrict__ y, int N)
{
    int gtid = blockIdx.x * blockDim.x + threadIdx.x;
    int n    = gtid >> 6;     // wave id = query id
    int lane = threadIdx.x & 63;
    if (n >= N) return;       // wave-uniform

    const int b   = idx_b[n];
    const int pos = idx_h[n] * Ww + idx_w[n];

    // ---- prologue: xq (broadcast), q, transformed query qk2 = LOG2E*qk ----
    float xq[Cc];
#pragma unroll
    for (int c = 0; c < Cc; ++c) xq[c] = x[b * CHW + c * HW + pos];

    float q[Cc];
#pragma unroll
    for (int o = 0; o < Cc; ++o) {
        float a = qb[o];
#pragma unroll
        for (int c = 0; c < Cc; ++c) a += qw[o * Cc + c] * xq[c];
        q[o] = a;
    }

    const float LOG2E = 1.4426950408889634f;
    float qk2[Cc];
#pragma unroll
    for (int c = 0; c < Cc; ++c) {
        float a = 0.f;
#pragma unroll
        for (int o = 0; o < Cc; ++o) a += q[o] * kw[o * Cc + c];
        qk2[c] = a * LOG2E;
    }

    const float4* Xb = x4 + b * (Cc * HW4);

    float m = -1e30f, l = 0.f;
    float acc[Cc] = {0.f, 0.f, 0.f, 0.f, 0.f};

    // ---- main loop: 16 iterations, 5 float4 loads each ----
#pragma unroll 2
    for (int p = lane; p < HW4; p += 64) {
        float4 xc[Cc];
#pragma unroll
        for (int c = 0; c < Cc; ++c) xc[c] = Xb[c * HW4 + p];

        float ex = qk2[0]*xc[0].x + qk2[1]*xc[1].x + qk2[2]*xc[2].x
                 + qk2[3]*xc[3].x + qk2[4]*xc[4].x;
        float ey = qk2[0]*xc[0].y + qk2[1]*xc[1].y + qk2[2]*xc[2].y
                 + qk2[3]*xc[3].y + qk2[4]*xc[4].y;
        float ez = qk2[0]*xc[0].z + qk2[1]*xc[1].z + qk2[2]*xc[2].z
                 + qk2[3]*xc[3].z + qk2[4]*xc[4].z;
        float ew = qk2[0]*xc[0].w + qk2[1]*xc[1].w + qk2[2]*xc[2].w
                 + qk2[3]*xc[3].w + qk2[4]*xc[4].w;

        float m4 = fmaxf(fmaxf(ex, ey), fmaxf(ez, ew));
        float nm = fmaxf(m, m4);
        float a  = fast_exp2(m - nm);     // rescale (0 on first iter)
        float w0 = fast_exp2(ex - nm);
        float w1 = fast_exp2(ey - nm);
        float w2 = fast_exp2(ez - nm);
        float w3 = fast_exp2(ew - nm);
        l = l * a + ((w0 + w1) + (w2 + w3));
#pragma unroll
        for (int c = 0; c < Cc; ++c)
            acc[c] = acc[c] * a +
                     ((w0 * xc[c].x + w1 * xc[c].y) +
                      (w2 * xc[c].z + w3 * xc[c].w));
        m = nm;
    }

    // ---- in-wave reduce: max-first (1 exp + plain-sum butterflies) ----
    float mm = m;
#pragma unroll
    for (int off = 32; off >= 1; off >>= 1)
        mm = fmaxf(mm, __shfl_xor(mm, off, 64));
    float a  = fast_exp2(m - mm);
    float ll = l * a;
    float ac[Cc];
#pragma unroll
    for (int c = 0; c < Cc; ++c) ac[c] = acc[c] * a;
#pragma unroll
    for (int off = 32; off >= 1; off >>= 1) {
        ll += __shfl_xor(ll, off, 64);
#pragma unroll
        for (int c = 0; c < Cc; ++c) ac[c] += __shfl_xor(ac[c], off, 64);
    }

    // ---- epilogue: apply vw/vb, scatter gamma*out + xi ----
    if (lane < Cc) {
        int c = lane;
        float dot = vw[c * Cc + 0] * ac[0] + vw[c * Cc + 1] * ac[1]
                  + vw[c * Cc + 2] * ac[2] + vw[c * Cc + 3] * ac[3]
                  + vw[c * Cc + 4] * ac[4];
        float outc = dot / ll + vb[c];
        // select xq[c] without dynamic register indexing
        float xv = xq[0];
        xv = (c == 1) ? xq[1] : xv;
        xv = (c == 2) ? xq[2] : xv;
        xv = (c == 3) ? xq[3] : xv;
        xv = (c == 4) ? xq[4] : xv;
        y[b * CHW + c * HW + pos] = gamma[0] * outc + xv;
    }
}

// ---------------------------------------------------------------------------
extern "C" void kernel_launch(void* const* d_in, const int* in_sizes, int n_in,
                              void* d_out, int out_size, void* d_ws, size_t ws_size,
                              hipStream_t stream) {
    const float* x     = (const float*)d_in[0];
    // d_in[1] = x_teature: unused by the reference
    const float* qw    = (const float*)d_in[2];
    const float* qb    = (const float*)d_in[3];
    const float* kw    = (const float*)d_in[4];
    // d_in[5] = kb: contributes a per-query constant to energy -> dropped
    //           (softmax is shift-invariant)
    const float* vw    = (const float*)d_in[6];
    const float* vb    = (const float*)d_in[7];
    const float* gamma = (const float*)d_in[8];
    const int*   idx_b = (const int*)d_in[9];
    const int*   idx_h = (const int*)d_in[10];
    const int*   idx_w = (const int*)d_in[11];
    const int    N     = in_sizes[9];   // idx_b element count (= index_len)

    float* y = (float*)d_out;

    // y starts as a copy of x; attn_direct scatters on top (ordered dispatch).
    hipMemcpyAsync(y, x, (size_t)Bq * CHW * sizeof(float),
                   hipMemcpyDeviceToDevice, stream);

    // one wave per query, 4 waves per 256-thread block
    const int blocks = (N + 3) / 4;
    attn_direct<<<blocks, 256, 0, stream>>>(
        x, (const float4*)x, qw, qb, kw, vw, vb, gamma,
        idx_b, idx_h, idx_w, y, N);
}